// Round 10
// baseline (178.945 us; speedup 1.0000x reference)
//
#include <hip/hip_runtime.h>
#include <hip/hip_bf16.h>
#include <cstdint>

// Problem constants
#define B_ 2
#define L_ 2048
#define E_ 1024
#define H_ 16
#define D_ 64
#define N3_ 3072
#define NCHUNK 32
#define CHUNK 64

typedef __attribute__((ext_vector_type(8))) short bf16x8;
typedef __attribute__((ext_vector_type(4))) float f32x4;

__device__ __forceinline__ unsigned short f2bf(float f) {
  unsigned u = __float_as_uint(f);
  unsigned r = (u + 0x7fffu + ((u >> 16) & 1u)) >> 16;  // RNE
  return (unsigned short)r;
}
__device__ __forceinline__ float bf2f(unsigned short u) {
  return __uint_as_float(((unsigned)u) << 16);
}

// ---------------------------------------------------------------------------
// fp32 -> bf16 conversion, all three tensors in one launch.
// ---------------------------------------------------------------------------
__global__ __launch_bounds__(256) void k_cvt_all(
    const float* __restrict__ x, const float* __restrict__ qkv_w,
    const float* __restrict__ out_w, unsigned short* __restrict__ xb,
    unsigned short* __restrict__ wqkv, unsigned short* __restrict__ wout) {
  const int i = blockIdx.x * 256 + threadIdx.x;
  const float* src;
  unsigned short* dst;
  int j;
  if (i < 1048576)      { src = x;     dst = xb;   j = i; }
  else if (i < 1835008) { src = qkv_w; dst = wqkv; j = i - 1048576; }
  else                  { src = out_w; dst = wout; j = i - 1835008; }
  float4 v = reinterpret_cast<const float4*>(src)[j];
  ushort4 o;
  o.x = f2bf(v.x); o.y = f2bf(v.y); o.z = f2bf(v.z); o.w = f2bf(v.w);
  reinterpret_cast<ushort4*>(dst)[j] = o;
}

// ---------------------------------------------------------------------------
// QKV GEMM: 256x192 tile, BK=64, 8 waves (2M x 4N), 8-phase, counted vmcnt,
// LDS XOR-swizzle, setprio, XCD swizzle. Grid 16x16 = 256 blocks = 1/CU.
// R7-verified ledger: stageB(t+1)@ph1 -> d^1, stageA(t+2)@ph3 -> d, vmcnt(4)
// @ph4 (retires A(t+1)+B(t+1) across two tiles' issue windows).
// Epilogue layout-fusion: writes Qb (l,d), Kb (l,d), Ktb (d,l per chunk),
// Vtb (e,l per chunk). No Vb.
// ---------------------------------------------------------------------------
__global__ __launch_bounds__(512, 2) void k_gemm256_qkv(
    const unsigned short* __restrict__ A,   // (4096,1024) bf16
    const unsigned short* __restrict__ Bm,  // (3072,1024) bf16
    const float* __restrict__ bias,
    unsigned short* __restrict__ Qb, unsigned short* __restrict__ Kb,
    unsigned short* __restrict__ Ktb, unsigned short* __restrict__ Vtb) {
  __shared__ short As[2][256 * 64];
  __shared__ short Bs[2][192 * 64];
  const int tid = threadIdx.x;
  const int lane = tid & 63, wave = tid >> 6;
  const int wm = wave >> 2, wn = wave & 3;
  const int bid0 = blockIdx.y * 16 + blockIdx.x;
  const int bid = (bid0 & 7) * 32 + (bid0 >> 3);  // bijective XCD swizzle
  const int m0 = (bid >> 4) * 256, n0 = (bid & 15) * 192;
  const int srow = tid >> 3, scol = (tid & 7) * 8;
  const int ssw = (srow & 7) * 8;
  const int l15 = lane & 15, l16 = lane >> 4;
  const int sw = (l15 & 7) * 8;
  const int NT = 16;

  f32x4 acc[8][3];
#pragma unroll
  for (int i = 0; i < 8; ++i)
#pragma unroll
    for (int j = 0; j < 3; ++j) acc[i][j] = (f32x4){0.f, 0.f, 0.f, 0.f};

  auto stageA = [&](int d, int kt) {  // 4 insts
#pragma unroll
    for (int i = 0; i < 4; ++i) {
      const int r = i * 64 + srow;
      const unsigned short* src = &A[(size_t)(m0 + r) * 1024 + kt * 64 + (scol ^ ssw)];
      __builtin_amdgcn_global_load_lds(
          (const __attribute__((address_space(1))) unsigned int*)src,
          (__attribute__((address_space(3))) unsigned int*)&As[d][r * 64 + scol], 16, 0, 0);
    }
  };
  auto stageB = [&](int d, int kt) {  // 3 insts
#pragma unroll
    for (int i = 0; i < 3; ++i) {
      const int r = i * 64 + srow;
      const unsigned short* src = &Bm[(size_t)(n0 + r) * 1024 + kt * 64 + (scol ^ ssw)];
      __builtin_amdgcn_global_load_lds(
          (const __attribute__((address_space(1))) unsigned int*)src,
          (__attribute__((address_space(3))) unsigned int*)&Bs[d][r * 64 + scol], 16, 0, 0);
    }
  };
  auto lda = [&](bf16x8 (&dv)[8], int d, int kh) {
#pragma unroll
    for (int mi = 0; mi < 8; ++mi) {
      const int r = wm * 128 + mi * 16 + l15;
      dv[mi] = *reinterpret_cast<const bf16x8*>(&As[d][r * 64 + ((l16 * 8 + kh * 32) ^ sw)]);
    }
  };
  auto ldb = [&](bf16x8 (&dv)[3], int d, int kh) {
#pragma unroll
    for (int ni = 0; ni < 3; ++ni) {
      const int r = wn * 48 + ni * 16 + l15;
      dv[ni] = *reinterpret_cast<const bf16x8*>(&Bs[d][r * 64 + ((l16 * 8 + kh * 32) ^ sw)]);
    }
  };
  auto quad = [&](const bf16x8 (&af)[8], const bf16x8 (&bf)[3], int nb, int ne) {
    __builtin_amdgcn_s_setprio(1);
#pragma unroll
    for (int mi = 0; mi < 8; ++mi)
      for (int nn = nb; nn < ne; ++nn)
        acc[mi][nn] = __builtin_amdgcn_mfma_f32_16x16x32_bf16(af[mi], bf[nn], acc[mi][nn], 0, 0, 0);
    __builtin_amdgcn_s_setprio(0);
  };

  // prologue (R7 ledger)
  stageA(0, 0); stageB(0, 0); stageA(1, 1);
  asm volatile("s_waitcnt vmcnt(4)" ::: "memory");
  __builtin_amdgcn_s_barrier();

  bf16x8 af0[8], af1[8], bf0[3], bf1[3];
  for (int t = 0; t < NT; ++t) {
    const int d = t & 1;
    // ph1: ds-read kh0; stage B(t+1)->d^1; MFMA kh0 ni{0,1}
    lda(af0, d, 0); ldb(bf0, d, 0);
    if (t + 1 < NT) stageB(d ^ 1, t + 1);
    __builtin_amdgcn_s_barrier();
    asm volatile("s_waitcnt lgkmcnt(0)" ::: "memory");
    __builtin_amdgcn_sched_barrier(0);
    quad(af0, bf0, 0, 2);
    __builtin_amdgcn_s_barrier();
    // ph2: ds-read kh1; MFMA kh0 ni{2}
    lda(af1, d, 1); ldb(bf1, d, 1);
    __builtin_amdgcn_s_barrier();
    asm volatile("s_waitcnt lgkmcnt(0)" ::: "memory");
    __builtin_amdgcn_sched_barrier(0);
    quad(af0, bf0, 2, 3);
    __builtin_amdgcn_s_barrier();
    // ph3: stage A(t+2)->d; MFMA kh1 ni{0,1}
    if (t + 2 < NT) stageA(d, t + 2);
    quad(af1, bf1, 0, 2);
    __builtin_amdgcn_s_barrier();
    // ph4: MFMA kh1 ni{2}; counted vmcnt -> t+1 resident
    quad(af1, bf1, 2, 3);
    if (t + 2 < NT) asm volatile("s_waitcnt vmcnt(4)" ::: "memory");
    else            asm volatile("s_waitcnt vmcnt(0)" ::: "memory");
    __builtin_amdgcn_s_barrier();
  }

  // epilogue: bias + relu + eps; Q/K row-major, K^T/V^T chunk-tiles
#pragma unroll
  for (int mi = 0; mi < 8; ++mi) {
#pragma unroll
    for (int ni = 0; ni < 3; ++ni) {
      const int col = n0 + wn * 48 + ni * 16 + l15;
      const float bv = bias[col];
      const int t = col >> 10, hd = col & 1023;
      const int h = hd >> 6, dd = hd & 63;
#pragma unroll
      for (int j = 0; j < 4; ++j) {
        const int row = m0 + wm * 128 + mi * 16 + l16 * 4 + j;
        const float val = acc[mi][ni][j] + bv;
        const int b = row >> 11, l = row & 2047;
        const int bh = b * 16 + h;
        const size_t dst = ((size_t)bh * 2048 + l) * 64 + dd;
        // chunk-transposed address: (bh,ch) tile, [dd][l&63]
        const size_t tdst = ((size_t)(bh * 32 + (l >> 6))) * 4096 + (size_t)dd * 64 + (l & 63);
        if (t == 0) {
          Qb[dst] = f2bf(fmaxf(val, 0.f) + 1e-6f);
        } else if (t == 1) {
          const unsigned short kv2 = f2bf(fmaxf(val, 0.f) + 1e-6f);
          Kb[dst] = kv2;
          Ktb[tdst] = kv2;
        } else {
          Vtb[tdst] = f2bf(val);
        }
      }
    }
  }
}

// ---------------------------------------------------------------------------
// Output GEMM: 256x64 tile, BK=64, 8 waves, R7-verified 8-phase schedule.
// ---------------------------------------------------------------------------
__global__ __launch_bounds__(512, 2) void k_gemm256_out(
    const unsigned short* __restrict__ A,   // attn (4096,1024) bf16
    const unsigned short* __restrict__ Bm,  // out_w (1024,1024) bf16
    const float* __restrict__ bias, float* __restrict__ O) {
  __shared__ short As[2][256 * 64];
  __shared__ short Bs[2][64 * 64];
  const int tid = threadIdx.x;
  const int lane = tid & 63, wave = tid >> 6;
  const int wm = wave >> 2, wn = wave & 3;
  const int bid0 = blockIdx.y * 16 + blockIdx.x;
  const int bid = (bid0 & 7) * 32 + (bid0 >> 3);  // bijective XCD swizzle
  const int m0 = (bid >> 4) * 256, n0 = (bid & 15) * 64;
  const int srow = tid >> 3, scol = (tid & 7) * 8;
  const int ssw = (srow & 7) * 8;
  const int l15 = lane & 15, l16 = lane >> 4;
  const int sw = (l15 & 7) * 8;
  const int NT = 16;

  f32x4 acc[8];
#pragma unroll
  for (int i = 0; i < 8; ++i) acc[i] = (f32x4){0.f, 0.f, 0.f, 0.f};

  auto stageA = [&](int d, int kt) {  // 4 insts
#pragma unroll
    for (int i = 0; i < 4; ++i) {
      const int r = i * 64 + srow;
      const unsigned short* src = &A[(size_t)(m0 + r) * 1024 + kt * 64 + (scol ^ ssw)];
      __builtin_amdgcn_global_load_lds(
          (const __attribute__((address_space(1))) unsigned int*)src,
          (__attribute__((address_space(3))) unsigned int*)&As[d][r * 64 + scol], 16, 0, 0);
    }
  };
  auto stageB = [&](int d, int kt) {  // 1 inst
    const unsigned short* src = &Bm[(size_t)(n0 + srow) * 1024 + kt * 64 + (scol ^ ssw)];
    __builtin_amdgcn_global_load_lds(
        (const __attribute__((address_space(1))) unsigned int*)src,
        (__attribute__((address_space(3))) unsigned int*)&Bs[d][srow * 64 + scol], 16, 0, 0);
  };
  auto lda = [&](bf16x8 (&dv)[8], int d, int kh) {
#pragma unroll
    for (int mi = 0; mi < 8; ++mi) {
      const int r = wm * 128 + mi * 16 + l15;
      dv[mi] = *reinterpret_cast<const bf16x8*>(&As[d][r * 64 + ((l16 * 8 + kh * 32) ^ sw)]);
    }
  };
  auto ldb = [&](bf16x8& dv, int d, int kh) {
    const int r = wn * 16 + l15;
    dv = *reinterpret_cast<const bf16x8*>(&Bs[d][r * 64 + ((l16 * 8 + kh * 32) ^ sw)]);
  };
  auto half = [&](const bf16x8 (&af)[8], const bf16x8& bf, int mb) {
    __builtin_amdgcn_s_setprio(1);
#pragma unroll
    for (int mi = mb; mi < mb + 4; ++mi)
      acc[mi] = __builtin_amdgcn_mfma_f32_16x16x32_bf16(af[mi], bf, acc[mi], 0, 0, 0);
    __builtin_amdgcn_s_setprio(0);
  };

  stageA(0, 0); stageB(0, 0); stageA(1, 1);
  asm volatile("s_waitcnt vmcnt(4)" ::: "memory");
  __builtin_amdgcn_s_barrier();

  bf16x8 af0[8], af1[8], bf0, bf1;
  for (int t = 0; t < NT; ++t) {
    const int d = t & 1;
    lda(af0, d, 0); ldb(bf0, d, 0);
    if (t + 1 < NT) stageB(d ^ 1, t + 1);
    __builtin_amdgcn_s_barrier();
    asm volatile("s_waitcnt lgkmcnt(0)" ::: "memory");
    __builtin_amdgcn_sched_barrier(0);
    half(af0, bf0, 0);
    __builtin_amdgcn_s_barrier();
    lda(af1, d, 1); ldb(bf1, d, 1);
    __builtin_amdgcn_s_barrier();
    asm volatile("s_waitcnt lgkmcnt(0)" ::: "memory");
    __builtin_amdgcn_sched_barrier(0);
    half(af0, bf0, 4);
    __builtin_amdgcn_s_barrier();
    if (t + 2 < NT) stageA(d, t + 2);
    half(af1, bf1, 0);
    __builtin_amdgcn_s_barrier();
    half(af1, bf1, 4);
    if (t + 2 < NT) asm volatile("s_waitcnt vmcnt(4)" ::: "memory");
    else            asm volatile("s_waitcnt vmcnt(0)" ::: "memory");
    __builtin_amdgcn_s_barrier();
  }

  const int col = n0 + wn * 16 + l15;
  const float bv = bias[col];
#pragma unroll
  for (int mi = 0; mi < 8; ++mi) {
#pragma unroll
    for (int j = 0; j < 4; ++j) {
      const int row = m0 + wm * 128 + mi * 16 + l16 * 4 + j;
      O[(size_t)row * 1024 + col] = acc[mi][j] + bv;
    }
  }
}

// ---------------------------------------------------------------------------
// Kernel B: per-(bh,chunk) KV-state via MFMA, ones-column trick.
// Fragments come straight from the GEMM-epilogue-written Ktb/Vtb — no LDS,
// no transpose, no barrier.
// ---------------------------------------------------------------------------
__global__ __launch_bounds__(128) void k_chunkB(
    const unsigned short* __restrict__ Ktb, const unsigned short* __restrict__ Vtb,
    unsigned short* __restrict__ STc) {
  const int tid = threadIdx.x;
  const int lane = tid & 63, w = tid >> 6;
  const int c = lane & 15, g = lane >> 4;
  const int bid = blockIdx.x;
  const size_t tb = (size_t)bid * 4096;
  bf16x8 kf[4][2], vf[2][2];
#pragma unroll
  for (int dt = 0; dt < 4; ++dt)
#pragma unroll
    for (int kh = 0; kh < 2; ++kh)
      kf[dt][kh] = *reinterpret_cast<const bf16x8*>(&Ktb[tb + (size_t)(dt * 16 + c) * 64 + g * 8 + kh * 32]);
#pragma unroll
  for (int ei = 0; ei < 2; ++ei)
#pragma unroll
    for (int kh = 0; kh < 2; ++kh)
      vf[ei][kh] = *reinterpret_cast<const bf16x8*>(&Vtb[tb + (size_t)((w * 2 + ei) * 16 + c) * 64 + g * 8 + kh * 32]);
  f32x4 acc[2][4];
#pragma unroll
  for (int ei = 0; ei < 2; ++ei)
#pragma unroll
    for (int dt = 0; dt < 4; ++dt) acc[ei][dt] = (f32x4){0.f, 0.f, 0.f, 0.f};
#pragma unroll
  for (int ei = 0; ei < 2; ++ei)
#pragma unroll
    for (int dt = 0; dt < 4; ++dt)
#pragma unroll
      for (int kh = 0; kh < 2; ++kh)
        acc[ei][dt] = __builtin_amdgcn_mfma_f32_16x16x32_bf16(vf[ei][kh], kf[dt][kh], acc[ei][dt], 0, 0, 0);
  const size_t stbase = (size_t)bid * 5120;
#pragma unroll
  for (int ei = 0; ei < 2; ++ei)
#pragma unroll
    for (int dt = 0; dt < 4; ++dt)
#pragma unroll
      for (int r = 0; r < 4; ++r)
        STc[stbase + (size_t)((w * 2 + ei) * 16 + 4 * g + r) * 64 + dt * 16 + c] = f2bf(acc[ei][dt][r]);
  if (w == 0) {
    const short one = (c == 0) ? (short)0x3F80 : (short)0;
    bf16x8 of;
#pragma unroll
    for (int r = 0; r < 8; ++r) of[r] = one;
    f32x4 az[4];
#pragma unroll
    for (int dt = 0; dt < 4; ++dt) az[dt] = (f32x4){0.f, 0.f, 0.f, 0.f};
#pragma unroll
    for (int dt = 0; dt < 4; ++dt)
#pragma unroll
      for (int kh = 0; kh < 2; ++kh)
        az[dt] = __builtin_amdgcn_mfma_f32_16x16x32_bf16(of, kf[dt][kh], az[dt], 0, 0, 0);
    if (g == 0) {
#pragma unroll
      for (int dt = 0; dt < 4; ++dt)
        STc[stbase + 64 * 64 + dt * 16 + c] = f2bf(az[dt][0]);
    }
  }
}

// ---------------------------------------------------------------------------
// Kernel C: element-parallel exclusive prefix over 32 chunks per (bh).
// ---------------------------------------------------------------------------
__global__ __launch_bounds__(256) void k_prefix2(const unsigned short* __restrict__ STc,
                                                 unsigned short* __restrict__ STb) {
  const int bh = blockIdx.x;
  const int e = blockIdx.y * 256 + threadIdx.x;
  if (e >= 4160) return;
  const size_t base = (size_t)bh * NCHUNK * 5120 + e;
  float run = 0.f;
  for (int cc = 0; cc < NCHUNK; ++cc) {
    const float t = bf2f(STc[base + (size_t)cc * 5120]);
    STb[base + (size_t)cc * 5120] = f2bf(run);
    run += t;
  }
}

// ---------------------------------------------------------------------------
// Kernel D: per-(bh,chunk) output via MFMA (swapped QK^T + ones-column den).
// ---------------------------------------------------------------------------
__global__ __launch_bounds__(256) void k_chunkD(
    const unsigned short* __restrict__ Qb, const unsigned short* __restrict__ Kb,
    const unsigned short* __restrict__ Vtb, const unsigned short* __restrict__ STb,
    unsigned short* __restrict__ attnb) {
  __shared__ __align__(16) unsigned short P[4][1024];
  const int tid = threadIdx.x;
  const int lane = tid & 63, lt = tid >> 6;
  const int c = lane & 15, g = lane >> 4;
  const int bid = blockIdx.x;
  const int bh = bid >> 5, ch = bid & 31;
  const int b = bh >> 4, h = bh & 15;
  const size_t qkbase = ((size_t)bh * L_ + (size_t)ch * CHUNK) * D_;
  bf16x8 q[2], k4[4][2], s[5][2], vt[4][2], pa[2];
#pragma unroll
  for (int kh = 0; kh < 2; ++kh)
    q[kh] = *reinterpret_cast<const bf16x8*>(&Qb[qkbase + (size_t)(lt * 16 + c) * 64 + g * 8 + kh * 32]);
#pragma unroll
  for (int jt = 0; jt < 4; ++jt)
#pragma unroll
    for (int kh = 0; kh < 2; ++kh)
      k4[jt][kh] = *reinterpret_cast<const bf16x8*>(&Kb[qkbase + (size_t)(jt * 16 + c) * 64 + g * 8 + kh * 32]);
  const size_t stbase = (size_t)bid * 5120;
#pragma unroll
  for (int et = 0; et < 5; ++et)
#pragma unroll
    for (int kh = 0; kh < 2; ++kh)
      s[et][kh] = *reinterpret_cast<const bf16x8*>(&STb[stbase + (size_t)(et * 16 + c) * 64 + g * 8 + kh * 32]);
#pragma unroll
  for (int et = 0; et < 4; ++et)
#pragma unroll
    for (int kh = 0; kh < 2; ++kh)
      vt[et][kh] = *reinterpret_cast<const bf16x8*>(&Vtb[(size_t)bid * 4096 + (size_t)(et * 16 + c) * 64 + g * 8 + kh * 32]);

  char* Pb = (char*)&P[lt][0];
  const int swz = (c & 7) << 4;
#pragma unroll
  for (int jt = 0; jt < 4; ++jt) {
    unsigned pk0 = 0, pk1 = 0;
    if (jt <= lt) {
      f32x4 a1 = (f32x4){0.f, 0.f, 0.f, 0.f};
#pragma unroll
      for (int kh = 0; kh < 2; ++kh)
        a1 = __builtin_amdgcn_mfma_f32_16x16x32_bf16(k4[jt][kh], q[kh], a1, 0, 0, 0);
      if (jt == lt) {
#pragma unroll
        for (int r = 0; r < 4; ++r) a1[r] = (4 * g + r <= c) ? a1[r] : 0.f;
      }
      pk0 = (unsigned)f2bf(a1[0]) | ((unsigned)f2bf(a1[1]) << 16);
      pk1 = (unsigned)f2bf(a1[2]) | ((unsigned)f2bf(a1[3]) << 16);
    }
    *reinterpret_cast<unsigned*>(Pb + ((c * 128 + 32 * jt + 8 * g + 0) ^ swz)) = pk0;
    *reinterpret_cast<unsigned*>(Pb + ((c * 128 + 32 * jt + 8 * g + 4) ^ swz)) = pk1;
  }
#pragma unroll
  for (int kh = 0; kh < 2; ++kh)
    pa[kh] = *reinterpret_cast<const bf16x8*>(Pb + (c * 128 + ((16 * g + 64 * kh) ^ swz)));

  f32x4 acc2[5];
#pragma unroll
  for (int et = 0; et < 5; ++et) acc2[et] = (f32x4){0.f, 0.f, 0.f, 0.f};
  const short one = (c == 0) ? (short)0x3F80 : (short)0;
  bf16x8 of;
#pragma unroll
  for (int r = 0; r < 8; ++r) of[r] = one;
#pragma unroll
  for (int et = 0; et < 5; ++et) {
#pragma unroll
    for (int kh = 0; kh < 2; ++kh) {
      acc2[et] = __builtin_amdgcn_mfma_f32_16x16x32_bf16(q[kh], s[et][kh], acc2[et], 0, 0, 0);
      bf16x8 vv = (et < 4) ? vt[et][kh] : of;
      acc2[et] = __builtin_amdgcn_mfma_f32_16x16x32_bf16(pa[kh], vv, acc2[et], 0, 0, 0);
    }
  }
  float inv[4];
#pragma unroll
  for (int r = 0; r < 4; ++r) {
    float dv = __shfl(acc2[4][r], lane & 48, 64);
    inv[r] = 1.f / fmaxf(dv, 1e-6f);
  }
  const size_t obase = ((size_t)b * L_ + (size_t)ch * CHUNK + (size_t)lt * 16) * E_ + (size_t)h * 64;
#pragma unroll
  for (int et = 0; et < 4; ++et)
#pragma unroll
    for (int r = 0; r < 4; ++r)
      attnb[obase + (size_t)(4 * g + r) * E_ + et * 16 + c] = f2bf(acc2[et][r] * inv[r]);
}

// ---------------------------------------------------------------------------
extern "C" void kernel_launch(void* const* d_in, const int* in_sizes, int n_in,
                              void* d_out, int out_size, void* d_ws, size_t ws_size,
                              hipStream_t stream) {
  const float* x = (const float*)d_in[0];
  const float* qkv_w = (const float*)d_in[1];
  const float* qkv_b = (const float*)d_in[2];
  const float* out_w = (const float*)d_in[3];
  const float* out_b = (const float*)d_in[4];
  float* out = (float*)d_out;

  const size_t SZ = (size_t)B_ * H_ * L_ * D_;  // 4,194,304
  char* p = (char*)d_ws;
  unsigned short* Qb = (unsigned short*)p;    p += SZ * 2;
  unsigned short* Kb = (unsigned short*)p;    p += SZ * 2;
  unsigned short* Ktb = (unsigned short*)p;   p += (size_t)1024 * 4096 * 2;
  unsigned short* Vtb = (unsigned short*)p;   p += (size_t)1024 * 4096 * 2;
  unsigned short* STc = (unsigned short*)p;   p += (size_t)1024 * 5120 * 2;
  unsigned short* STb = (unsigned short*)p;   p += (size_t)1024 * 5120 * 2;
  unsigned short* xb = (unsigned short*)p;    p += SZ * 2;
  unsigned short* wqkv = (unsigned short*)p;  p += (size_t)N3_ * E_ * 2;
  unsigned short* wout = (unsigned short*)p;  p += (size_t)E_ * E_ * 2;
  unsigned short* attnb = (unsigned short*)p; p += SZ * 2;

  dim3 blk(256);
  k_cvt_all<<<dim3(8192), blk, 0, stream>>>(x, qkv_w, out_w, xb, wqkv, wout);
  k_gemm256_qkv<<<dim3(16, 16), dim3(512), 0, stream>>>(xb, wqkv, qkv_b, Qb, Kb, Ktb, Vtb);
  k_chunkB<<<dim3(1024), dim3(128), 0, stream>>>(Ktb, Vtb, STc);
  k_prefix2<<<dim3(32, 17), blk, 0, stream>>>(STc, STb);
  k_chunkD<<<dim3(1024), blk, 0, stream>>>(Qb, Kb, Vtb, STb, attnb);
  k_gemm256_out<<<dim3(16, 16), dim3(512), 0, stream>>>(attnb, wout, out_b, out);
}

// Round 12
// 164.212 us; speedup vs baseline: 1.0897x; 1.0897x over previous
//
#include <hip/hip_runtime.h>
#include <hip/hip_bf16.h>
#include <cstdint>

// Problem constants
#define B_ 2
#define L_ 2048
#define E_ 1024
#define H_ 16
#define D_ 64
#define N3_ 3072
#define NCHUNK 32
#define CHUNK 64

typedef __attribute__((ext_vector_type(8))) short bf16x8;
typedef __attribute__((ext_vector_type(4))) float f32x4;

__device__ __forceinline__ unsigned short f2bf(float f) {
  unsigned u = __float_as_uint(f);
  unsigned r = (u + 0x7fffu + ((u >> 16) & 1u)) >> 16;  // RNE
  return (unsigned short)r;
}
__device__ __forceinline__ float bf2f(unsigned short u) {
  return __uint_as_float(((unsigned)u) << 16);
}

// ---------------------------------------------------------------------------
// fp32 -> bf16 conversion, all three tensors in one launch.
// ---------------------------------------------------------------------------
__global__ __launch_bounds__(256) void k_cvt_all(
    const float* __restrict__ x, const float* __restrict__ qkv_w,
    const float* __restrict__ out_w, unsigned short* __restrict__ xb,
    unsigned short* __restrict__ wqkv, unsigned short* __restrict__ wout) {
  const int i = blockIdx.x * 256 + threadIdx.x;
  const float* src;
  unsigned short* dst;
  int j;
  if (i < 1048576)      { src = x;     dst = xb;   j = i; }
  else if (i < 1835008) { src = qkv_w; dst = wqkv; j = i - 1048576; }
  else                  { src = out_w; dst = wout; j = i - 1835008; }
  float4 v = reinterpret_cast<const float4*>(src)[j];
  ushort4 o;
  o.x = f2bf(v.x); o.y = f2bf(v.y); o.z = f2bf(v.z); o.w = f2bf(v.w);
  reinterpret_cast<ushort4*>(dst)[j] = o;
}

// ---------------------------------------------------------------------------
// QKV GEMM: 128x128 tile, BK=64, 8 waves (2M x 4N, wave tile 64x32),
// 8-phase schedule (R7-verified structure), counted vmcnt, XOR-swizzle,
// setprio, XCD swizzle. LDS 64KB -> 2 blocks/CU; grid 768 = 3 blocks/CU.
// Ledger (2 gload_lds insts per stage):
//   prologue A0,B0,A1 -> vmcnt(2) (t0 resident, A1 in flight).
//   tile t (dbuf d): ph1 stage B(t+1)->d^1; ph3 stage A(t+2)->d (tile-t
//   reads of d closed by ph2 barrier); ph4 vmcnt(2) retires A(t+1)+B(t+1).
// ---------------------------------------------------------------------------
__global__ __launch_bounds__(512, 2) void k_gemm128_qkv(
    const unsigned short* __restrict__ A,   // (4096,1024) bf16
    const unsigned short* __restrict__ Bm,  // (3072,1024) bf16
    const float* __restrict__ bias,
    unsigned short* __restrict__ Qb, unsigned short* __restrict__ Kb,
    unsigned short* __restrict__ Vb) {
  __shared__ short As[2][128 * 64];
  __shared__ short Bs[2][128 * 64];
  const int tid = threadIdx.x;
  const int lane = tid & 63, wave = tid >> 6;
  const int wm = wave >> 2, wn = wave & 3;
  const int bid0 = blockIdx.x;
  const int bid = (bid0 & 7) * 96 + (bid0 >> 3);  // bijective XCD chunk swizzle
  const int m0 = (bid / 24) * 128, n0 = (bid % 24) * 128;
  const int srow = tid >> 3, scol = (tid & 7) * 8;  // 64 rows / gload inst
  const int ssw = (srow & 7) * 8;                   // source pre-swizzle
  const int l15 = lane & 15, l16 = lane >> 4;
  const int sw = (l15 & 7) * 8;                     // read-side swizzle
  const int NT = 16;

  f32x4 acc[4][2];
#pragma unroll
  for (int i = 0; i < 4; ++i)
#pragma unroll
    for (int j = 0; j < 2; ++j) acc[i][j] = (f32x4){0.f, 0.f, 0.f, 0.f};

  auto stageA = [&](int d, int kt) {  // 2 insts
#pragma unroll
    for (int i = 0; i < 2; ++i) {
      const int r = i * 64 + srow;
      const unsigned short* src = &A[(size_t)(m0 + r) * 1024 + kt * 64 + (scol ^ ssw)];
      __builtin_amdgcn_global_load_lds(
          (const __attribute__((address_space(1))) unsigned int*)src,
          (__attribute__((address_space(3))) unsigned int*)&As[d][r * 64 + scol], 16, 0, 0);
    }
  };
  auto stageB = [&](int d, int kt) {  // 2 insts
#pragma unroll
    for (int i = 0; i < 2; ++i) {
      const int r = i * 64 + srow;
      const unsigned short* src = &Bm[(size_t)(n0 + r) * 1024 + kt * 64 + (scol ^ ssw)];
      __builtin_amdgcn_global_load_lds(
          (const __attribute__((address_space(1))) unsigned int*)src,
          (__attribute__((address_space(3))) unsigned int*)&Bs[d][r * 64 + scol], 16, 0, 0);
    }
  };
  auto lda = [&](bf16x8 (&dv)[4], int d, int kh) {
#pragma unroll
    for (int mi = 0; mi < 4; ++mi) {
      const int r = wm * 64 + mi * 16 + l15;
      dv[mi] = *reinterpret_cast<const bf16x8*>(&As[d][r * 64 + ((l16 * 8 + kh * 32) ^ sw)]);
    }
  };
  auto ldb = [&](bf16x8 (&dv)[2], int d, int kh) {
#pragma unroll
    for (int ni = 0; ni < 2; ++ni) {
      const int r = wn * 32 + ni * 16 + l15;
      dv[ni] = *reinterpret_cast<const bf16x8*>(&Bs[d][r * 64 + ((l16 * 8 + kh * 32) ^ sw)]);
    }
  };
  auto quad = [&](const bf16x8 (&af)[4], const bf16x8 (&bf)[2], int nn) {
    __builtin_amdgcn_s_setprio(1);
#pragma unroll
    for (int mi = 0; mi < 4; ++mi)
      acc[mi][nn] = __builtin_amdgcn_mfma_f32_16x16x32_bf16(af[mi], bf[nn], acc[mi][nn], 0, 0, 0);
    __builtin_amdgcn_s_setprio(0);
  };

  // prologue
  stageA(0, 0); stageB(0, 0); stageA(1, 1);
  asm volatile("s_waitcnt vmcnt(2)" ::: "memory");
  __builtin_amdgcn_s_barrier();

  bf16x8 af0[4], af1[4], bf0[2], bf1[2];
  for (int t = 0; t < NT; ++t) {
    const int d = t & 1;
    // ph1: ds-read kh0; stage B(t+1)->d^1; MFMA kh0 ni0
    lda(af0, d, 0); ldb(bf0, d, 0);
    if (t + 1 < NT) stageB(d ^ 1, t + 1);
    __builtin_amdgcn_s_barrier();
    asm volatile("s_waitcnt lgkmcnt(0)" ::: "memory");
    __builtin_amdgcn_sched_barrier(0);
    quad(af0, bf0, 0);
    __builtin_amdgcn_s_barrier();
    // ph2: ds-read kh1; MFMA kh0 ni1
    lda(af1, d, 1); ldb(bf1, d, 1);
    __builtin_amdgcn_s_barrier();
    asm volatile("s_waitcnt lgkmcnt(0)" ::: "memory");
    __builtin_amdgcn_sched_barrier(0);
    quad(af0, bf0, 1);
    __builtin_amdgcn_s_barrier();
    // ph3: stage A(t+2)->d; MFMA kh1 ni0
    if (t + 2 < NT) stageA(d, t + 2);
    quad(af1, bf1, 0);
    __builtin_amdgcn_s_barrier();
    // ph4: MFMA kh1 ni1; counted vmcnt -> t+1 resident
    quad(af1, bf1, 1);
    if (t + 2 < NT) asm volatile("s_waitcnt vmcnt(2)" ::: "memory");
    else            asm volatile("s_waitcnt vmcnt(0)" ::: "memory");
    __builtin_amdgcn_s_barrier();
  }

  // epilogue: scatter bf16 Q/K/V with bias + relu + eps (R7 layout)
#pragma unroll
  for (int mi = 0; mi < 4; ++mi) {
#pragma unroll
    for (int ni = 0; ni < 2; ++ni) {
      const int col = n0 + wn * 32 + ni * 16 + l15;
      const float bv = bias[col];
      const int t = col >> 10, hd = col & 1023;
      const int h = hd >> 6, dd = hd & 63;
#pragma unroll
      for (int j = 0; j < 4; ++j) {
        const int row = m0 + wm * 64 + mi * 16 + l16 * 4 + j;
        const float val = acc[mi][ni][j] + bv;
        const int b = row >> 11, l = row & 2047;
        const size_t dst = (((size_t)(b * 16 + h)) * 2048 + l) * 64 + dd;
        if (t == 0)      Qb[dst] = f2bf(fmaxf(val, 0.f) + 1e-6f);
        else if (t == 1) Kb[dst] = f2bf(fmaxf(val, 0.f) + 1e-6f);
        else             Vb[dst] = f2bf(val);
      }
    }
  }
}

// ---------------------------------------------------------------------------
// Output GEMM: 256x64 tile, BK=64, 8 waves, R7-verified 8-phase schedule.
// ---------------------------------------------------------------------------
__global__ __launch_bounds__(512, 2) void k_gemm256_out(
    const unsigned short* __restrict__ A,   // attn (4096,1024) bf16
    const unsigned short* __restrict__ Bm,  // out_w (1024,1024) bf16
    const float* __restrict__ bias, float* __restrict__ O) {
  __shared__ short As[2][256 * 64];
  __shared__ short Bs[2][64 * 64];
  const int tid = threadIdx.x;
  const int lane = tid & 63, wave = tid >> 6;
  const int wm = wave >> 2, wn = wave & 3;
  const int bid0 = blockIdx.y * 16 + blockIdx.x;
  const int bid = (bid0 & 7) * 32 + (bid0 >> 3);  // bijective XCD swizzle
  const int m0 = (bid >> 4) * 256, n0 = (bid & 15) * 64;
  const int srow = tid >> 3, scol = (tid & 7) * 8;
  const int ssw = (srow & 7) * 8;
  const int l15 = lane & 15, l16 = lane >> 4;
  const int sw = (l15 & 7) * 8;
  const int NT = 16;

  f32x4 acc[8];
#pragma unroll
  for (int i = 0; i < 8; ++i) acc[i] = (f32x4){0.f, 0.f, 0.f, 0.f};

  auto stageA = [&](int d, int kt) {  // 4 insts
#pragma unroll
    for (int i = 0; i < 4; ++i) {
      const int r = i * 64 + srow;
      const unsigned short* src = &A[(size_t)(m0 + r) * 1024 + kt * 64 + (scol ^ ssw)];
      __builtin_amdgcn_global_load_lds(
          (const __attribute__((address_space(1))) unsigned int*)src,
          (__attribute__((address_space(3))) unsigned int*)&As[d][r * 64 + scol], 16, 0, 0);
    }
  };
  auto stageB = [&](int d, int kt) {  // 1 inst
    const unsigned short* src = &Bm[(size_t)(n0 + srow) * 1024 + kt * 64 + (scol ^ ssw)];
    __builtin_amdgcn_global_load_lds(
        (const __attribute__((address_space(1))) unsigned int*)src,
        (__attribute__((address_space(3))) unsigned int*)&Bs[d][srow * 64 + scol], 16, 0, 0);
  };
  auto lda = [&](bf16x8 (&dv)[8], int d, int kh) {
#pragma unroll
    for (int mi = 0; mi < 8; ++mi) {
      const int r = wm * 128 + mi * 16 + l15;
      dv[mi] = *reinterpret_cast<const bf16x8*>(&As[d][r * 64 + ((l16 * 8 + kh * 32) ^ sw)]);
    }
  };
  auto ldb = [&](bf16x8& dv, int d, int kh) {
    const int r = wn * 16 + l15;
    dv = *reinterpret_cast<const bf16x8*>(&Bs[d][r * 64 + ((l16 * 8 + kh * 32) ^ sw)]);
  };
  auto half = [&](const bf16x8 (&af)[8], const bf16x8& bf, int mb) {
    __builtin_amdgcn_s_setprio(1);
#pragma unroll
    for (int mi = mb; mi < mb + 4; ++mi)
      acc[mi] = __builtin_amdgcn_mfma_f32_16x16x32_bf16(af[mi], bf, acc[mi], 0, 0, 0);
    __builtin_amdgcn_s_setprio(0);
  };

  stageA(0, 0); stageB(0, 0); stageA(1, 1);
  asm volatile("s_waitcnt vmcnt(4)" ::: "memory");
  __builtin_amdgcn_s_barrier();

  bf16x8 af0[8], af1[8], bf0, bf1;
  for (int t = 0; t < NT; ++t) {
    const int d = t & 1;
    lda(af0, d, 0); ldb(bf0, d, 0);
    if (t + 1 < NT) stageB(d ^ 1, t + 1);
    __builtin_amdgcn_s_barrier();
    asm volatile("s_waitcnt lgkmcnt(0)" ::: "memory");
    __builtin_amdgcn_sched_barrier(0);
    half(af0, bf0, 0);
    __builtin_amdgcn_s_barrier();
    lda(af1, d, 1); ldb(bf1, d, 1);
    __builtin_amdgcn_s_barrier();
    asm volatile("s_waitcnt lgkmcnt(0)" ::: "memory");
    __builtin_amdgcn_sched_barrier(0);
    half(af0, bf0, 4);
    __builtin_amdgcn_s_barrier();
    if (t + 2 < NT) stageA(d, t + 2);
    half(af1, bf1, 0);
    __builtin_amdgcn_s_barrier();
    half(af1, bf1, 4);
    if (t + 2 < NT) asm volatile("s_waitcnt vmcnt(4)" ::: "memory");
    else            asm volatile("s_waitcnt vmcnt(0)" ::: "memory");
    __builtin_amdgcn_s_barrier();
  }

  const int col = n0 + wn * 16 + l15;
  const float bv = bias[col];
#pragma unroll
  for (int mi = 0; mi < 8; ++mi) {
#pragma unroll
    for (int j = 0; j < 4; ++j) {
      const int row = m0 + wm * 128 + mi * 16 + l16 * 4 + j;
      O[(size_t)row * 1024 + col] = acc[mi][j] + bv;
    }
  }
}

// ---------------------------------------------------------------------------
// Kernel B (R7 version): per-(bh,chunk) KV-state via MFMA, ones-column trick.
// LDS scalar transpose of K,V; persists V^T fragments for kernel D.
// ---------------------------------------------------------------------------
__global__ __launch_bounds__(128) void k_chunkB(
    const unsigned short* __restrict__ Kb, const unsigned short* __restrict__ Vb,
    unsigned short* __restrict__ STc, unsigned short* __restrict__ Vtb) {
  __shared__ __align__(16) unsigned short Kt[64 * 72];  // (d, l)
  __shared__ __align__(16) unsigned short Vt[64 * 72];  // (e, l)
  const int tid = threadIdx.x;
  const int lane = tid & 63, w = tid >> 6;
  const int c = lane & 15, g = lane >> 4;
  const int bid = blockIdx.x;
  const int bh = bid >> 5, ch = bid & 31;
  const size_t base = ((size_t)bh * L_ + (size_t)ch * CHUNK) * D_;
  const int l = tid >> 1, hf = tid & 1;
  bf16x8 kv[4], vv[4];
#pragma unroll
  for (int i = 0; i < 4; ++i) {
    kv[i] = *reinterpret_cast<const bf16x8*>(&Kb[base + (size_t)l * 64 + hf * 32 + i * 8]);
    vv[i] = *reinterpret_cast<const bf16x8*>(&Vb[base + (size_t)l * 64 + hf * 32 + i * 8]);
  }
#pragma unroll
  for (int i = 0; i < 4; ++i)
#pragma unroll
    for (int r = 0; r < 8; ++r) {
      const int d = hf * 32 + i * 8 + r;
      Kt[d * 72 + l] = (unsigned short)kv[i][r];
      Vt[d * 72 + l] = (unsigned short)vv[i][r];
    }
  __syncthreads();
  bf16x8 kf[4][2], vf[2][2];
#pragma unroll
  for (int dt = 0; dt < 4; ++dt)
#pragma unroll
    for (int kh = 0; kh < 2; ++kh)
      kf[dt][kh] = *reinterpret_cast<const bf16x8*>(&Kt[(dt * 16 + c) * 72 + g * 8 + kh * 32]);
#pragma unroll
  for (int ei = 0; ei < 2; ++ei)
#pragma unroll
    for (int kh = 0; kh < 2; ++kh)
      vf[ei][kh] = *reinterpret_cast<const bf16x8*>(&Vt[((w * 2 + ei) * 16 + c) * 72 + g * 8 + kh * 32]);
  f32x4 acc[2][4];
#pragma unroll
  for (int ei = 0; ei < 2; ++ei)
#pragma unroll
    for (int dt = 0; dt < 4; ++dt) acc[ei][dt] = (f32x4){0.f, 0.f, 0.f, 0.f};
#pragma unroll
  for (int ei = 0; ei < 2; ++ei)
#pragma unroll
    for (int dt = 0; dt < 4; ++dt)
#pragma unroll
      for (int kh = 0; kh < 2; ++kh)
        acc[ei][dt] = __builtin_amdgcn_mfma_f32_16x16x32_bf16(vf[ei][kh], kf[dt][kh], acc[ei][dt], 0, 0, 0);
  const size_t stbase = (size_t)bid * 5120;
#pragma unroll
  for (int ei = 0; ei < 2; ++ei)
#pragma unroll
    for (int dt = 0; dt < 4; ++dt)
#pragma unroll
      for (int r = 0; r < 4; ++r)
        STc[stbase + (size_t)((w * 2 + ei) * 16 + 4 * g + r) * 64 + dt * 16 + c] = f2bf(acc[ei][dt][r]);
#pragma unroll
  for (int ei = 0; ei < 2; ++ei)
#pragma unroll
    for (int kh = 0; kh < 2; ++kh)
      *reinterpret_cast<bf16x8*>(&Vtb[(size_t)bid * 4096 + ((w * 2 + ei) * 16 + c) * 64 + g * 8 + kh * 32]) = vf[ei][kh];
  if (w == 0) {
    const short one = (c == 0) ? (short)0x3F80 : (short)0;
    bf16x8 of;
#pragma unroll
    for (int r = 0; r < 8; ++r) of[r] = one;
    f32x4 az[4];
#pragma unroll
    for (int dt = 0; dt < 4; ++dt) az[dt] = (f32x4){0.f, 0.f, 0.f, 0.f};
#pragma unroll
    for (int dt = 0; dt < 4; ++dt)
#pragma unroll
      for (int kh = 0; kh < 2; ++kh)
        az[dt] = __builtin_amdgcn_mfma_f32_16x16x32_bf16(of, kf[dt][kh], az[dt], 0, 0, 0);
    if (g == 0) {
#pragma unroll
      for (int dt = 0; dt < 4; ++dt)
        STc[stbase + 64 * 64 + dt * 16 + c] = f2bf(az[dt][0]);
    }
  }
}

// ---------------------------------------------------------------------------
// Kernel C: element-parallel exclusive prefix over 32 chunks per (bh).
// ---------------------------------------------------------------------------
__global__ __launch_bounds__(256) void k_prefix2(const unsigned short* __restrict__ STc,
                                                 unsigned short* __restrict__ STb) {
  const int bh = blockIdx.x;
  const int e = blockIdx.y * 256 + threadIdx.x;
  if (e >= 4160) return;
  const size_t base = (size_t)bh * NCHUNK * 5120 + e;
  float run = 0.f;
  for (int cc = 0; cc < NCHUNK; ++cc) {
    const float t = bf2f(STc[base + (size_t)cc * 5120]);
    STb[base + (size_t)cc * 5120] = f2bf(run);
    run += t;
  }
}

// ---------------------------------------------------------------------------
// Kernel D: per-(bh,chunk) output via MFMA (swapped QK^T + ones-column den).
// ---------------------------------------------------------------------------
__global__ __launch_bounds__(256) void k_chunkD(
    const unsigned short* __restrict__ Qb, const unsigned short* __restrict__ Kb,
    const unsigned short* __restrict__ Vtb, const unsigned short* __restrict__ STb,
    unsigned short* __restrict__ attnb) {
  __shared__ __align__(16) unsigned short P[4][1024];
  const int tid = threadIdx.x;
  const int lane = tid & 63, lt = tid >> 6;
  const int c = lane & 15, g = lane >> 4;
  const int bid = blockIdx.x;
  const int bh = bid >> 5, ch = bid & 31;
  const int b = bh >> 4, h = bh & 15;
  const size_t qkbase = ((size_t)bh * L_ + (size_t)ch * CHUNK) * D_;
  bf16x8 q[2], k4[4][2], s[5][2], vt[4][2], pa[2];
#pragma unroll
  for (int kh = 0; kh < 2; ++kh)
    q[kh] = *reinterpret_cast<const bf16x8*>(&Qb[qkbase + (size_t)(lt * 16 + c) * 64 + g * 8 + kh * 32]);
#pragma unroll
  for (int jt = 0; jt < 4; ++jt)
#pragma unroll
    for (int kh = 0; kh < 2; ++kh)
      k4[jt][kh] = *reinterpret_cast<const bf16x8*>(&Kb[qkbase + (size_t)(jt * 16 + c) * 64 + g * 8 + kh * 32]);
  const size_t stbase = (size_t)bid * 5120;
#pragma unroll
  for (int et = 0; et < 5; ++et)
#pragma unroll
    for (int kh = 0; kh < 2; ++kh)
      s[et][kh] = *reinterpret_cast<const bf16x8*>(&STb[stbase + (size_t)(et * 16 + c) * 64 + g * 8 + kh * 32]);
#pragma unroll
  for (int et = 0; et < 4; ++et)
#pragma unroll
    for (int kh = 0; kh < 2; ++kh)
      vt[et][kh] = *reinterpret_cast<const bf16x8*>(&Vtb[(size_t)bid * 4096 + (size_t)(et * 16 + c) * 64 + g * 8 + kh * 32]);

  char* Pb = (char*)&P[lt][0];
  const int swz = (c & 7) << 4;
#pragma unroll
  for (int jt = 0; jt < 4; ++jt) {
    unsigned pk0 = 0, pk1 = 0;
    if (jt <= lt) {
      f32x4 a1 = (f32x4){0.f, 0.f, 0.f, 0.f};
#pragma unroll
      for (int kh = 0; kh < 2; ++kh)
        a1 = __builtin_amdgcn_mfma_f32_16x16x32_bf16(k4[jt][kh], q[kh], a1, 0, 0, 0);
      if (jt == lt) {
#pragma unroll
        for (int r = 0; r < 4; ++r) a1[r] = (4 * g + r <= c) ? a1[r] : 0.f;
      }
      pk0 = (unsigned)f2bf(a1[0]) | ((unsigned)f2bf(a1[1]) << 16);
      pk1 = (unsigned)f2bf(a1[2]) | ((unsigned)f2bf(a1[3]) << 16);
    }
    *reinterpret_cast<unsigned*>(Pb + ((c * 128 + 32 * jt + 8 * g + 0) ^ swz)) = pk0;
    *reinterpret_cast<unsigned*>(Pb + ((c * 128 + 32 * jt + 8 * g + 4) ^ swz)) = pk1;
  }
#pragma unroll
  for (int kh = 0; kh < 2; ++kh)
    pa[kh] = *reinterpret_cast<const bf16x8*>(Pb + (c * 128 + ((16 * g + 64 * kh) ^ swz)));

  f32x4 acc2[5];
#pragma unroll
  for (int et = 0; et < 5; ++et) acc2[et] = (f32x4){0.f, 0.f, 0.f, 0.f};
  const short one = (c == 0) ? (short)0x3F80 : (short)0;
  bf16x8 of;
#pragma unroll
  for (int r = 0; r < 8; ++r) of[r] = one;
#pragma unroll
  for (int et = 0; et < 5; ++et) {
#pragma unroll
    for (int kh = 0; kh < 2; ++kh) {
      acc2[et] = __builtin_amdgcn_mfma_f32_16x16x32_bf16(q[kh], s[et][kh], acc2[et], 0, 0, 0);
      bf16x8 vv = (et < 4) ? vt[et][kh] : of;
      acc2[et] = __builtin_amdgcn_mfma_f32_16x16x32_bf16(pa[kh], vv, acc2[et], 0, 0, 0);
    }
  }
  float inv[4];
#pragma unroll
  for (int r = 0; r < 4; ++r) {
    float dv = __shfl(acc2[4][r], lane & 48, 64);
    inv[r] = 1.f / fmaxf(dv, 1e-6f);
  }
  const size_t obase = ((size_t)b * L_ + (size_t)ch * CHUNK + (size_t)lt * 16) * E_ + (size_t)h * 64;
#pragma unroll
  for (int et = 0; et < 4; ++et)
#pragma unroll
    for (int r = 0; r < 4; ++r)
      attnb[obase + (size_t)(4 * g + r) * E_ + et * 16 + c] = f2bf(acc2[et][r] * inv[r]);
}

// ---------------------------------------------------------------------------
extern "C" void kernel_launch(void* const* d_in, const int* in_sizes, int n_in,
                              void* d_out, int out_size, void* d_ws, size_t ws_size,
                              hipStream_t stream) {
  const float* x = (const float*)d_in[0];
  const float* qkv_w = (const float*)d_in[1];
  const float* qkv_b = (const float*)d_in[2];
  const float* out_w = (const float*)d_in[3];
  const float* out_b = (const float*)d_in[4];
  float* out = (float*)d_out;

  const size_t SZ = (size_t)B_ * H_ * L_ * D_;  // 4,194,304
  char* p = (char*)d_ws;
  unsigned short* Qb = (unsigned short*)p;    p += SZ * 2;
  unsigned short* Kb = (unsigned short*)p;    p += SZ * 2;
  unsigned short* Vb = (unsigned short*)p;    p += SZ * 2;
  unsigned short* Vtb = (unsigned short*)p;   p += (size_t)1024 * 4096 * 2;
  unsigned short* STc = (unsigned short*)p;   p += (size_t)1024 * 5120 * 2;
  unsigned short* STb = (unsigned short*)p;   p += (size_t)1024 * 5120 * 2;
  unsigned short* xb = (unsigned short*)p;    p += SZ * 2;
  unsigned short* wqkv = (unsigned short*)p;  p += (size_t)N3_ * E_ * 2;
  unsigned short* wout = (unsigned short*)p;  p += (size_t)E_ * E_ * 2;
  unsigned short* attnb = (unsigned short*)p; p += SZ * 2;

  dim3 blk(256);
  k_cvt_all<<<dim3(8192), blk, 0, stream>>>(x, qkv_w, out_w, xb, wqkv, wout);
  // QKV projection (M=4096, N=3072, K=1024), 128x128 8-phase, grid=768 (3/CU)
  k_gemm128_qkv<<<dim3(768), dim3(512), 0, stream>>>(xb, wqkv, qkv_b, Qb, Kb, Vb);
  // chunked scan, MFMA (R7-verified versions)
  k_chunkB<<<dim3(1024), dim3(128), 0, stream>>>(Kb, Vb, STc, Vtb);
  k_prefix2<<<dim3(32, 17), blk, 0, stream>>>(STc, STb);
  k_chunkD<<<dim3(1024), blk, 0, stream>>>(Qb, Kb, Vtb, STb, attnb);
  // output projection (M=4096, N=1024, K=1024), 256x64 8-phase
  k_gemm256_out<<<dim3(16, 16), dim3(512), 0, stream>>>(attnb, wout, out_b, out);
}